// Round 2
// baseline (1997.285 us; speedup 1.0000x reference)
//
#include <hip/hip_runtime.h>
#include <float.h>

#define BATCH 16
#define NPTS  65536
#define NP    64      // NUM_PATCHES
#define PS    32      // PATCH_SIZE

// All selection decisions (FPS argmax, KNN top-32) are made on float64
// distances computed from the f32 inputs. Every product of two f32 values is
// EXACT in f64, so results are bit-identical to a numpy float64 reference
// independent of FMA contraction; only the written add order matters and it
// mirrors numpy: ((a+b)+c), d2 = (c2+p2) - 2*dot.
// Keys pack trunc-48-bit f64 ordering bits with a 16-bit point index
// (NPTS=65536 fits), giving (distance, index) lexicographic order in one u64.

__device__ __forceinline__ unsigned long long enc64(double d) {
    unsigned long long u = (unsigned long long)__double_as_longlong(d);
    return u ^ ((u >> 63) ? 0xFFFFFFFFFFFFFFFFull : 0x8000000000000000ull);
}

// ---------------------------------------------------------------------------
// FPS: 16 WGs per batch, 256 threads, 16 points/thread in VGPRs.
// Per round: f64 min_d update + local argmax, WG reduce, one device-scope
// atomicMax into slot[b][it], per-batch spin barrier, read winner.
// key = (f64bits(d) & ~0xFFFF) | (~idx & 0xFFFF): max => (d desc, idx asc).
// ---------------------------------------------------------------------------
__global__ __launch_bounds__(256, 2)
void fps_kernel(const float* __restrict__ pts,
                float* __restrict__ centers,               // [16][64][3]
                unsigned long long* __restrict__ slots,    // [16][64]
                unsigned long long* __restrict__ counters) // [16][16]
{
#pragma clang fp contract(off)
    const int b  = blockIdx.x & 15;
    const int wg = blockIdx.x >> 4;
    const int t  = threadIdx.x;
    const float* __restrict__ P = pts + (size_t)b * NPTS * 3;

    float x[16], y[16], z[16];
    double md[16];
    const int gi0 = wg * 4096 + t;
#pragma unroll
    for (int k = 0; k < 16; ++k) {
        int i = gi0 + (k << 8);
        x[k] = P[3*i+0]; y[k] = P[3*i+1]; z[k] = P[3*i+2];
        md[k] = DBL_MAX;
    }

    double cx = (double)P[0], cy = (double)P[1], cz = (double)P[2]; // start idx 0
    if (wg == 0 && t == 0) {
        float* c0 = centers + b * (NP*3);
        c0[0] = P[0]; c0[1] = P[1]; c0[2] = P[2];
    }

    __shared__ unsigned long long wbest[4];
    __shared__ unsigned long long bkey;

    unsigned long long* slot_b = slots + b * NP;
    unsigned long long* cnt    = counters + (size_t)b * 16;

    for (int it = 0; it < NP - 1; ++it) {
        double bd = -1.0; int bi = 0;
#pragma unroll
        for (int k = 0; k < 16; ++k) {
            double dx = (double)x[k] - cx;
            double dy = (double)y[k] - cy;
            double dz = (double)z[k] - cz;
            double d  = (dx*dx + dy*dy) + dz*dz;   // numpy add order (products exact)
            double m  = fmin(md[k], d);
            md[k] = m;
            if (m > bd) { bd = m; bi = gi0 + (k << 8); }  // strict >: first index wins
        }
        // bd >= 0 -> raw f64 bits are order-preserving
        unsigned long long db = (unsigned long long)__double_as_longlong(bd);
        unsigned long long key = (db & 0xFFFFFFFFFFFF0000ull)
                               | (unsigned long long)((~bi) & 0xFFFF);
#pragma unroll
        for (int off = 32; off > 0; off >>= 1) {
            unsigned long long o = __shfl_xor(key, off, 64);
            if (o > key) key = o;
        }
        if ((t & 63) == 0) wbest[t >> 6] = key;
        __syncthreads();
        if (t == 0) {
            unsigned long long k0 = wbest[0];
            if (wbest[1] > k0) k0 = wbest[1];
            if (wbest[2] > k0) k0 = wbest[2];
            if (wbest[3] > k0) k0 = wbest[3];
            atomicMax(slot_b + it, k0);                    // device scope
            __threadfence();
            __hip_atomic_fetch_add(cnt, 1ull, __ATOMIC_ACQ_REL, __HIP_MEMORY_SCOPE_AGENT);
            unsigned long long target = (unsigned long long)(it + 1) * 16u;
            while (__hip_atomic_load(cnt, __ATOMIC_ACQUIRE, __HIP_MEMORY_SCOPE_AGENT) < target)
                __builtin_amdgcn_s_sleep(2);
            bkey = __hip_atomic_load(slot_b + it, __ATOMIC_RELAXED, __HIP_MEMORY_SCOPE_AGENT);
        }
        __syncthreads();
        int sel = (int)((~bkey) & 0xFFFFull);
        cx = (double)P[3*sel+0]; cy = (double)P[3*sel+1]; cz = (double)P[3*sel+2];
        if (wg == 0 && t == 0) {
            float* c = centers + b*(NP*3) + (it+1)*3;
            c[0] = P[3*sel+0]; c[1] = P[3*sel+1]; c[2] = P[3*sel+2];
        }
    }
}

// ---------------------------------------------------------------------------
// KNN + gather: one wave per center. Lane scans 1024 strided points keeping
// its top-32 as u64 keys (trunc-48 f64 distance | 16-bit idx) -> lexicographic
// (d2 asc, idx asc) == lax.top_k order. 32 wave-min extraction rounds emit
// patch rows already sorted.
// ---------------------------------------------------------------------------
#define SENT 0xFFFFFFFFFFFFFFFFull

__global__ __launch_bounds__(256, 2)
void knn_kernel(const float* __restrict__ pts,
                const float* __restrict__ centers,
                float* __restrict__ patches)
{
#pragma clang fp contract(off)
    const int lane = threadIdx.x & 63;
    const int wid  = threadIdx.x >> 6;
    const int c    = blockIdx.x * 4 + wid;   // 0..1023
    const int b    = c >> 6;
    const float* __restrict__ P = pts + (size_t)b * NPTS * 3;

    const float cxf = centers[3*c+0], cyf = centers[3*c+1], czf = centers[3*c+2];
    const double cx = (double)cxf, cy = (double)cyf, cz = (double)czf;
    const double c2 = (cx*cx + cy*cy) + cz*cz;   // products exact in f64

    unsigned long long cand[32];
#pragma unroll
    for (int j = 0; j < 32; ++j) cand[j] = SENT;
    unsigned long long wkmax = SENT;
    int wpos = 0;

    for (int k = 0; k < NPTS/64; ++k) {
        int i = (k << 6) + lane;             // coalesced across lanes
        double px = (double)P[3*i+0], py = (double)P[3*i+1], pz = (double)P[3*i+2];
        double p2 = (px*px + py*py) + pz*pz;
        double dt = (cx*px + cy*py) + cz*pz;
        double d2 = (c2 + p2) - 2.0*dt;      // reference formula/order, f64
        unsigned long long nk = (enc64(d2) & 0xFFFFFFFFFFFF0000ull)
                              | (unsigned long long)(unsigned)i;
        if (nk < wkmax) {                    // maintain 32 smallest keys
            cand[wpos] = nk;
            unsigned long long mx = cand[0]; int mp = 0;
#pragma unroll
            for (int j = 1; j < 32; ++j)
                if (cand[j] > mx) { mx = cand[j]; mp = j; }
            wpos = mp; wkmax = mx;
        }
    }

    // 32 extraction rounds: wave-global min key -> sorted output (top_k order)
    for (int r = 0; r < PS; ++r) {
        unsigned long long mn = cand[0]; int mp = 0;
#pragma unroll
        for (int j = 1; j < 32; ++j)
            if (cand[j] < mn) { mn = cand[j]; mp = j; }
        unsigned long long wm = mn;
#pragma unroll
        for (int off = 32; off > 0; off >>= 1) {
            unsigned long long o = __shfl_xor(wm, off, 64);
            if (o < wm) wm = o;
        }
        if (wm == mn) {                      // unique winner (idx in key)
            int i = (int)(mn & 0xFFFFull);
            float* o = patches + (((size_t)c * PS) + r) * 3;
            o[0] = P[3*i+0] - cxf;
            o[1] = P[3*i+1] - cyf;
            o[2] = P[3*i+2] - czf;
#pragma unroll
            for (int j = 0; j < 32; ++j) if (j == mp) cand[j] = SENT;
        }
    }
}

extern "C" void kernel_launch(void* const* d_in, const int* in_sizes, int n_in,
                              void* d_out, int out_size, void* d_ws, size_t ws_size,
                              hipStream_t stream)
{
    const float* pts = (const float*)d_in[0];
    float* out      = (float*)d_out;
    float* patches  = out;                          // [16][64][32][3] = 98304
    float* centers  = out + (size_t)BATCH*NP*PS*3;  // [16][64][3]     = 3072

    unsigned long long* slots    = (unsigned long long*)d_ws;  // [16][64]
    unsigned long long* counters = slots + BATCH*NP;           // [16][16]

    hipMemsetAsync(d_ws, 0, (size_t)(BATCH*NP + BATCH*16) * sizeof(unsigned long long), stream);
    fps_kernel<<<dim3(256), dim3(256), 0, stream>>>(pts, centers, slots, counters);
    knn_kernel<<<dim3(256), dim3(256), 0, stream>>>(pts, centers, patches);
}

// Round 3
// 594.765 us; speedup vs baseline: 3.3581x; 3.3581x over previous
//
#include <hip/hip_runtime.h>
#include <float.h>

#define BATCH 16
#define NPTS  65536
#define NP    64      // NUM_PATCHES
#define PS    32      // PATCH_SIZE

// All selection decisions (FPS argmax, KNN top-32) use float64 distances from
// f32 inputs (products of f32 are exact in f64 -> bit-identical to numpy f64
// regardless of FMA). Expression order mirrors numpy: ((a+b)+c),
// d2 = (c2+p2) - 2*dot.  Keys: trunc-48-bit f64 ordering bits | 16-bit index
// (NPTS=65536 fits) -> (distance, index) lexicographic in one u64.

__device__ __forceinline__ unsigned long long enc64(double d) {
    unsigned long long u = (unsigned long long)__double_as_longlong(d);
    return u ^ ((u >> 63) ? 0xFFFFFFFFFFFFFFFFull : 0x8000000000000000ull);
}

// ---------------------------------------------------------------------------
// FPS: 16 WGs per batch (blockIdx = wg*16 + b -> all 16 WGs of batch b map to
// XCD b%8 under round-robin), 256 threads, 16 points/thread in VGPRs.
// Per-round sync: each WG release-stores its best key (bit63 set => nonzero)
// into slots[b][it][wg]; every WG acquire-polls the 16-entry line and takes
// the max locally. No atomics, no broadcast round-trip.
// key = bit63 | (f64bits(d) & ~0xFFFF) | (~idx & 0xFFFF): max => (d desc, idx asc).
// ---------------------------------------------------------------------------
__global__ __launch_bounds__(256, 2)
void fps_kernel(const float* __restrict__ pts,
                float* __restrict__ centers,               // [16][64][3]
                unsigned long long* __restrict__ slots)    // [16][63][16], pre-zeroed
{
#pragma clang fp contract(off)
    const int b  = blockIdx.x & 15;
    const int wg = blockIdx.x >> 4;
    const int t  = threadIdx.x;
    const float* __restrict__ P = pts + (size_t)b * NPTS * 3;

    float x[16], y[16], z[16];
    double md[16];
    const int gi0 = wg * 4096 + t;
#pragma unroll
    for (int k = 0; k < 16; ++k) {
        int i = gi0 + (k << 8);
        x[k] = P[3*i+0]; y[k] = P[3*i+1]; z[k] = P[3*i+2];
        md[k] = DBL_MAX;
    }

    double cx = (double)P[0], cy = (double)P[1], cz = (double)P[2]; // start idx 0
    if (wg == 0 && t == 0) {
        float* c0 = centers + b * (NP*3);
        c0[0] = P[0]; c0[1] = P[1]; c0[2] = P[2];
    }

    __shared__ unsigned long long wbest[4];
    __shared__ unsigned long long skey[16];

    unsigned long long* slot_it = slots + (size_t)b * 63 * 16;

    for (int it = 0; it < NP - 1; ++it) {
        double bd = -1.0; int bi = 0;
#pragma unroll
        for (int k = 0; k < 16; ++k) {
            double dx = (double)x[k] - cx;
            double dy = (double)y[k] - cy;
            double dz = (double)z[k] - cz;
            double d  = (dx*dx + dy*dy) + dz*dz;   // numpy add order (products exact)
            double m  = fmin(md[k], d);
            md[k] = m;
            if (m > bd) { bd = m; bi = gi0 + (k << 8); }  // strict >: first index wins
        }
        unsigned long long db  = (unsigned long long)__double_as_longlong(bd); // bd>=0
        unsigned long long key = 0x8000000000000000ull
                               | (db & 0xFFFFFFFFFFFF0000ull)
                               | (unsigned long long)((~bi) & 0xFFFF);
#pragma unroll
        for (int off = 32; off > 0; off >>= 1) {
            unsigned long long o = __shfl_xor(key, off, 64);
            if (o > key) key = o;
        }
        if ((t & 63) == 0) wbest[t >> 6] = key;
        __syncthreads();
        if (t == 0) {
            unsigned long long k0 = wbest[0];
            if (wbest[1] > k0) k0 = wbest[1];
            if (wbest[2] > k0) k0 = wbest[2];
            if (wbest[3] > k0) k0 = wbest[3];
            __hip_atomic_store(slot_it + wg, k0, __ATOMIC_RELEASE, __HIP_MEMORY_SCOPE_AGENT);
        }
        if (t < 16) {
            unsigned long long v;
            do {
                v = __hip_atomic_load(slot_it + t, __ATOMIC_ACQUIRE, __HIP_MEMORY_SCOPE_AGENT);
            } while (v == 0);
            skey[t] = v;
        }
        __syncthreads();
        unsigned long long bk = skey[0];
#pragma unroll
        for (int j = 1; j < 16; ++j) if (skey[j] > bk) bk = skey[j];
        int sel = (int)((~bk) & 0xFFFFull);
        cx = (double)P[3*sel+0]; cy = (double)P[3*sel+1]; cz = (double)P[3*sel+2];
        if (wg == 0 && t == 0) {
            float* c = centers + b*(NP*3) + (it+1)*3;
            c[0] = P[3*sel+0]; c[1] = P[3*sel+1]; c[2] = P[3*sel+2];
        }
        __syncthreads();   // protect skey/wbest reuse next round
        slot_it += 16;
    }
}

// ---------------------------------------------------------------------------
// KNN + gather: 1024 WGs (one per center), 4 waves each; wave w scans points
// [w*16384, (w+1)*16384). Wave-distributed top-32: lane j<32 holds buffer
// slot j (u64 key in a VGPR), lanes>=32 hold 0; threshold = wave-max key
// (uniform). Accepts are wave-uniform events (~200/wave). The 4 sub-buffers
// (union superset of global top-32) merge in LDS via 32 exact extraction
// rounds -> rows emitted already in lax.top_k sorted order.
// blockIdx = ci*16 + b  -> batch b's 64 WGs on XCD b%8 (768 KB stream stays
// in one XCD's L2).
// ---------------------------------------------------------------------------
#define SENT 0xFFFFFFFFFFFFFFFFull

__global__ __launch_bounds__(256, 4)
void knn_kernel(const float* __restrict__ pts,
                const float* __restrict__ centers,
                float* __restrict__ patches)
{
#pragma clang fp contract(off)
    const int lane = threadIdx.x & 63;
    const int wid  = threadIdx.x >> 6;
    const int b    = blockIdx.x & 15;
    const int ci   = blockIdx.x >> 4;        // 0..63 within batch
    const int c    = b * NP + ci;            // global center 0..1023
    const float* __restrict__ P = pts + (size_t)b * NPTS * 3;

    const float cxf = centers[3*c+0], cyf = centers[3*c+1], czf = centers[3*c+2];
    const double cx = (double)cxf, cy = (double)cyf, cz = (double)czf;
    const double c2 = (cx*cx + cy*cy) + cz*cz;

    unsigned long long slot  = (lane < PS) ? SENT : 0ull;
    unsigned long long wkmax = SENT;

    const int base = wid * (NPTS / 4);
    for (int k = 0; k < NPTS / 4 / 64; ++k) {          // 256 iterations
        int i = base + (k << 6) + lane;                // coalesced
        double px = (double)P[3*i+0], py = (double)P[3*i+1], pz = (double)P[3*i+2];
        double p2 = (px*px + py*py) + pz*pz;
        double dt = (cx*px + cy*py) + cz*pz;
        double d2 = (c2 + p2) - 2.0*dt;                // reference formula/order
        unsigned long long nk = (enc64(d2) & 0xFFFFFFFFFFFF0000ull)
                              | (unsigned long long)(i & 0xFFFF);
        unsigned long long m = __ballot(nk < wkmax);
        while (m) {
            int l = __ffsll(m) - 1; m &= m - 1;
            unsigned long long kl = __shfl(nk, l, 64);     // uniform
            if (kl < wkmax) {                              // uniform branch
                unsigned long long rm = __ballot(slot == wkmax);
                int rl = __ffsll(rm) - 1;                  // unique keys -> 1 owner
                if (lane == rl) slot = kl;
                unsigned long long v = slot;
#pragma unroll
                for (int off = 32; off > 0; off >>= 1) {
                    unsigned long long o = __shfl_xor(v, off, 64);
                    if (o > v) v = o;
                }
                wkmax = v;
            }
        }
    }

    __shared__ unsigned long long lkeys[128];
    if (lane < PS) lkeys[wid * PS + lane] = slot;
    __syncthreads();

    // 32 extraction rounds over the 128 merged candidates. All 4 waves run
    // identical rounds (redundant but idempotent: same SENT marks, same
    // output values); barrier per round keeps LDS views consistent.
    for (int r = 0; r < PS; ++r) {
        unsigned long long k0 = lkeys[lane];
        unsigned long long k1 = lkeys[64 + lane];
        unsigned long long mv = (k0 < k1) ? k0 : k1;
        unsigned long long wm = mv;
#pragma unroll
        for (int off = 32; off > 0; off >>= 1) {
            unsigned long long o = __shfl_xor(wm, off, 64);
            if (o < wm) wm = o;
        }
        int sidx = (k0 == wm) ? lane : ((k1 == wm) ? 64 + lane : -1);
        if (sidx >= 0) {                    // exactly one lane per wave
            int i = (int)(wm & 0xFFFFull);
            float* o = patches + (((size_t)c * PS) + r) * 3;
            o[0] = P[3*i+0] - cxf;
            o[1] = P[3*i+1] - cyf;
            o[2] = P[3*i+2] - czf;
            lkeys[sidx] = SENT;
        }
        __syncthreads();
    }
}

extern "C" void kernel_launch(void* const* d_in, const int* in_sizes, int n_in,
                              void* d_out, int out_size, void* d_ws, size_t ws_size,
                              hipStream_t stream)
{
    const float* pts = (const float*)d_in[0];
    float* out      = (float*)d_out;
    float* patches  = out;                          // [16][64][32][3] = 98304
    float* centers  = out + (size_t)BATCH*NP*PS*3;  // [16][64][3]     = 3072

    unsigned long long* slots = (unsigned long long*)d_ws;   // [16][63][16]

    hipMemsetAsync(d_ws, 0, (size_t)BATCH * 63 * 16 * sizeof(unsigned long long), stream);
    fps_kernel<<<dim3(256), dim3(256), 0, stream>>>(pts, centers, slots);
    knn_kernel<<<dim3(1024), dim3(256), 0, stream>>>(pts, centers, patches);
}

// Round 4
// 274.089 us; speedup vs baseline: 7.2870x; 2.1700x over previous
//
#include <hip/hip_runtime.h>
#include <float.h>

#define BATCH 16
#define NPTS  65536
#define NP    64      // NUM_PATCHES
#define PS    32      // PATCH_SIZE

// Selection math (FPS argmax, KNN top-32) is float64 on f32 inputs (products
// of f32 exact in f64 -> bit-identical to numpy f64 regardless of FMA), with
// numpy expression order: ((a+b)+c), d2 = (c2+p2) - 2*dot, contract(off).
// Keys: trunc-48-bit f64 ordering bits | 16-bit index -> (dist, idx) lex order.

__device__ __forceinline__ unsigned long long enc64(double d) {
    unsigned long long u = (unsigned long long)__double_as_longlong(d);
    return u ^ ((u >> 63) ? 0xFFFFFFFFFFFFFFFFull : 0x8000000000000000ull);
}
__device__ __forceinline__ unsigned enc32(float f) {
    unsigned u = __float_as_uint(f);
    return u ^ ((u >> 31) ? 0xFFFFFFFFu : 0x80000000u);
}
__device__ __forceinline__ float dec32(unsigned e) {
    unsigned u = (e & 0x80000000u) ? (e ^ 0x80000000u) : ~e;
    return __uint_as_float(u);
}

// ---------------------------------------------------------------------------
// FPS: 16 WGs per batch (blockIdx = wg*16+b -> all WGs of batch b on XCD b%8),
// 256 threads, 16 pts/thread in VGPRs. Cross-WG sync uses RELAXED agent
// atomics only (the 64-bit key IS the data; P immutable) -> no per-poll cache
// invalidate / per-store L2 writeback that acquire/release agent scope costs
// on non-coherent per-XCD L2s. Distinct slot line per round -> no ABA.
// ---------------------------------------------------------------------------
__global__ __launch_bounds__(256, 2)
void fps_kernel(const float* __restrict__ pts,
                float* __restrict__ centers,               // [16][64][3]
                unsigned long long* __restrict__ slots)    // [16][63][16], zeroed
{
#pragma clang fp contract(off)
    const int b  = blockIdx.x & 15;
    const int wg = blockIdx.x >> 4;
    const int t  = threadIdx.x;
    const float* __restrict__ P = pts + (size_t)b * NPTS * 3;

    float x[16], y[16], z[16];
    double md[16];
    const int gi0 = wg * 4096 + t;
#pragma unroll
    for (int k = 0; k < 16; ++k) {
        int i = gi0 + (k << 8);
        x[k] = P[3*i+0]; y[k] = P[3*i+1]; z[k] = P[3*i+2];
        md[k] = DBL_MAX;
    }

    double cx = (double)P[0], cy = (double)P[1], cz = (double)P[2]; // start idx 0
    if (wg == 0 && t == 0) {
        float* c0 = centers + b * (NP*3);
        c0[0] = P[0]; c0[1] = P[1]; c0[2] = P[2];
    }

    __shared__ unsigned long long wbest[4];
    __shared__ unsigned long long skey[16];

    unsigned long long* slot_it = slots + (size_t)b * 63 * 16;

    for (int it = 0; it < NP - 1; ++it) {
        double bd = -1.0; int bi = 0;
#pragma unroll
        for (int k = 0; k < 16; ++k) {
            double dx = (double)x[k] - cx;
            double dy = (double)y[k] - cy;
            double dz = (double)z[k] - cz;
            double d  = (dx*dx + dy*dy) + dz*dz;   // numpy add order (products exact)
            double m  = fmin(md[k], d);
            md[k] = m;
            if (m > bd) { bd = m; bi = gi0 + (k << 8); }  // strict >: first index wins
        }
        unsigned long long db  = (unsigned long long)__double_as_longlong(bd); // bd>=0
        unsigned long long key = 0x8000000000000000ull
                               | (db & 0xFFFFFFFFFFFF0000ull)
                               | (unsigned long long)((~bi) & 0xFFFF);
#pragma unroll
        for (int off = 32; off > 0; off >>= 1) {
            unsigned long long o = __shfl_xor(key, off, 64);
            if (o > key) key = o;
        }
        if ((t & 63) == 0) wbest[t >> 6] = key;
        __syncthreads();
        if (t == 0) {
            unsigned long long k0 = wbest[0];
            if (wbest[1] > k0) k0 = wbest[1];
            if (wbest[2] > k0) k0 = wbest[2];
            if (wbest[3] > k0) k0 = wbest[3];
            __hip_atomic_store(slot_it + wg, k0, __ATOMIC_RELAXED, __HIP_MEMORY_SCOPE_AGENT);
        }
        if (t < 16) {
            unsigned long long v;
            do {
                v = __hip_atomic_load(slot_it + t, __ATOMIC_RELAXED, __HIP_MEMORY_SCOPE_AGENT);
            } while (v == 0);
            skey[t] = v;
        }
        __syncthreads();
        unsigned long long bk = skey[0];
#pragma unroll
        for (int j = 1; j < 16; ++j) if (skey[j] > bk) bk = skey[j];
        int sel = (int)((~bk) & 0xFFFFull);
        cx = (double)P[3*sel+0]; cy = (double)P[3*sel+1]; cz = (double)P[3*sel+2];
        if (wg == 0 && t == 0) {
            float* c = centers + b*(NP*3) + (it+1)*3;
            c[0] = P[3*sel+0]; c[1] = P[3*sel+1]; c[2] = P[3*sel+2];
        }
        __syncthreads();   // protect skey/wbest reuse next round
        slot_it += 16;
    }
}

// ---------------------------------------------------------------------------
// KNN + gather: 1024 WGs (one per center), 4 waves; wave w scans its 16384-pt
// quarter. Pass 1 (f32): per-lane top-2 smallest d2 (3 branchless ops/pt).
// theta = 32nd smallest of the 128 pooled lane candidates (any subset's 32nd
// >= full subset's 32nd -> valid bound), found by 32-step bit-binary-search
// on ballot counts. Pass 2 (f32 rescan): hits (d2 <= theta + 4e-3; margin >>
// 2x max f32-vs-f64 error ~2e-4) compute the exact f64 key and LDS-append.
// Wave 0 extracts the 32 smallest of <=512 candidates (8 regs/lane) in sorted
// order = lax.top_k order, writes patches.
// ---------------------------------------------------------------------------
#define SENT 0xFFFFFFFFFFFFFFFFull

__global__ __launch_bounds__(256, 4)
void knn_kernel(const float* __restrict__ pts,
                const float* __restrict__ centers,
                float* __restrict__ patches)
{
    const int lane = threadIdx.x & 63;
    const int wid  = threadIdx.x >> 6;
    const int b    = blockIdx.x & 15;
    const int ci   = blockIdx.x >> 4;        // 0..63 within batch
    const int c    = b * NP + ci;            // global center 0..1023
    const float* __restrict__ P = pts + (size_t)b * NPTS * 3;

    const float cxf = centers[3*c+0], cyf = centers[3*c+1], czf = centers[3*c+2];
    const float c2f = cxf*cxf + cyf*cyf + czf*czf;   // approx path, contraction ok

    double cx, cy, cz, c2;
    {
#pragma clang fp contract(off)
        cx = (double)cxf; cy = (double)cyf; cz = (double)czf;
        c2 = (cx*cx + cy*cy) + cz*cz;
    }

    const int base = wid * (NPTS / 4);

    // ---- pass 1: per-lane top-2 (f32) ----
    float s0 = FLT_MAX, s1 = FLT_MAX;
    {
        const float* p = P + 3 * (base + lane);
        for (int k = 0; k < NPTS/4/64; ++k) {
            float px = p[0], py = p[1], pz = p[2];
            p += 192;
            float p2 = px*px + py*py + pz*pz;
            float dt = cxf*px + cyf*py + czf*pz;
            float d2 = (c2f + p2) - 2.0f*dt;
            float mx = fmaxf(d2, s0);
            s0 = fminf(s0, d2);
            s1 = fminf(s1, mx);
        }
    }
    // theta: minimal enc key t with #{lane candidates <= t} >= 32 (uniform)
    unsigned e0 = enc32(s0), e1 = enc32(s1);
    unsigned ans = 0;
    for (int bit = 31; bit >= 0; --bit) {
        unsigned test = ans | ((1u << bit) - 1u);
        int cnt = __popcll(__ballot(e0 <= test)) + __popcll(__ballot(e1 <= test));
        if (cnt < 32) ans |= (1u << bit);
    }
    const float theta = dec32(ans) + 4.0e-3f;

    // ---- pass 2: filtered exact f64 keys -> LDS buffer ----
    __shared__ unsigned long long lbuf[4][128];
    int cbase = 0;
    {
        const float* p = P + 3 * (base + lane);
        int i = base + lane;
        for (int k = 0; k < NPTS/4/64; ++k) {
            float px = p[0], py = p[1], pz = p[2];
            p += 192;
            float p2 = px*px + py*py + pz*pz;
            float dt = cxf*px + cyf*py + czf*pz;
            float d2 = (c2f + p2) - 2.0f*dt;
            bool hit = (d2 <= theta);
            unsigned long long m = __ballot(hit);
            if (m) {
                if (hit) {
                    double d2x;
                    {
#pragma clang fp contract(off)
                        double px_ = (double)px, py_ = (double)py, pz_ = (double)pz;
                        double p2_ = (px_*px_ + py_*py_) + pz_*pz_;
                        double dt_ = (cx*px_ + cy*py_) + cz*pz_;
                        d2x = (c2 + p2_) - 2.0*dt_;
                    }
                    unsigned long long key = (enc64(d2x) & 0xFFFFFFFFFFFF0000ull)
                                           | (unsigned long long)(i & 0xFFFF);
                    int pos = cbase + (int)__popcll(m & ((1ull << lane) - 1ull));
                    if (pos < 128) lbuf[wid][pos] = key;
                }
                cbase += (int)__popcll(m);
            }
            i += 64;
        }
    }
    if (cbase > 128) cbase = 128;
    for (int j = lane; j < 128; j += 64)
        if (j >= cbase) lbuf[wid][j] = SENT;
    __syncthreads();

    // ---- wave 0: extract 32 smallest (sorted) of the 512 merged candidates ----
    if (wid == 0) {
        unsigned long long rg[8];
        const unsigned long long* lb = &lbuf[0][0];
#pragma unroll
        for (int j = 0; j < 8; ++j) rg[j] = lb[lane * 8 + j];
        for (int r = 0; r < PS; ++r) {
            unsigned long long mn = rg[0]; int mp = 0;
#pragma unroll
            for (int j = 1; j < 8; ++j) if (rg[j] < mn) { mn = rg[j]; mp = j; }
            unsigned long long wm = mn;
#pragma unroll
            for (int off = 32; off > 0; off >>= 1) {
                unsigned long long o = __shfl_xor(wm, off, 64);
                if (o < wm) wm = o;
            }
            if (wm == mn) {               // unique owner (keys unique by idx)
#pragma unroll
                for (int j = 0; j < 8; ++j) if (j == mp) rg[j] = SENT;
            }
            if (lane == 0) {
                int i = (int)(wm & 0xFFFFull);
                float* o = patches + (((size_t)c * PS) + r) * 3;
                o[0] = P[3*i+0] - cxf;
                o[1] = P[3*i+1] - cyf;
                o[2] = P[3*i+2] - czf;
            }
        }
    }
}

extern "C" void kernel_launch(void* const* d_in, const int* in_sizes, int n_in,
                              void* d_out, int out_size, void* d_ws, size_t ws_size,
                              hipStream_t stream)
{
    const float* pts = (const float*)d_in[0];
    float* out      = (float*)d_out;
    float* patches  = out;                          // [16][64][32][3] = 98304
    float* centers  = out + (size_t)BATCH*NP*PS*3;  // [16][64][3]     = 3072

    unsigned long long* slots = (unsigned long long*)d_ws;   // [16][63][16]

    hipMemsetAsync(d_ws, 0, (size_t)BATCH * 63 * 16 * sizeof(unsigned long long), stream);
    fps_kernel<<<dim3(256), dim3(256), 0, stream>>>(pts, centers, slots);
    knn_kernel<<<dim3(1024), dim3(256), 0, stream>>>(pts, centers, patches);
}